// Round 2
// baseline (884.828 us; speedup 1.0000x reference)
//
#include <hip/hip_runtime.h>

#define G    128          // 4*HID
#define HID  32
#define EMB  16
#define BB   256
#define TT   2048

__device__ __forceinline__ float bf2f(unsigned short u) {
    return __uint_as_float(((unsigned)u) << 16);
}
__device__ __forceinline__ unsigned short f2bf(float f) {
    unsigned x = __float_as_uint(f);
    return (unsigned short)((x + 0x7FFFu + ((x >> 16) & 1u)) >> 16);  // RNE
}
__device__ __forceinline__ float rdl(float v, int k) {
    return __int_as_float(__builtin_amdgcn_readlane(__float_as_int(v), k));
}
__device__ __forceinline__ float sigm(float x) {
    const float e = __expf(-x);
    return __builtin_amdgcn_rcpf(1.f + e);
}
__device__ __forceinline__ float tanh_f(float x) {
    const float e = __expf(-2.f * x);
    return (1.f - e) * __builtin_amdgcn_rcpf(1.f + e);
}

// ---------------------------------------------------------------------------
// Dtype detector. Reads first 64 32-bit words of bias (256B: exactly the bf16
// buffer size; first half of the fp32 buffer — safe either way).
//   fp32 holding bf16-rounded values -> all low halves zero        -> flag=1
//   raw fp32 -> some low half decodes to huge/NaN bf16             -> flag=1
//   true bf16 -> small nonzero values everywhere                   -> flag=0
// ---------------------------------------------------------------------------
__global__ void detect_kernel(const unsigned int* __restrict__ bias_w,
                              int* __restrict__ flag) {
    if (threadIdx.x == 0 && blockIdx.x == 0) {
        bool evens_zero = true, anybig = false;
        for (int i = 0; i < 64; ++i) {
            const unsigned u  = bias_w[i];
            const unsigned lo = u & 0xFFFFu, hi = u >> 16;
            const float vlo = __uint_as_float(lo << 16);
            const float vhi = __uint_as_float(hi << 16);
            if (lo != 0u) evens_zero = false;
            if (!(fabsf(vlo) < 1e6f) || !(fabsf(vhi) < 1e6f)) anybig = true;
        }
        *flag = (evens_zero || anybig) ? 1 : 0;
    }
}

// ---------------------------------------------------------------------------
// zx[bt][j] = emb[tokens[bt]] @ Wk[:,j] + b[j]   (fp32 out to workspace)
// ---------------------------------------------------------------------------
__global__ __launch_bounds__(256) void zx_kernel(
    const int* __restrict__ tokens, const void* __restrict__ emb,
    const void* __restrict__ Wk, const void* __restrict__ bias,
    float* __restrict__ zx, const int* __restrict__ flag)
{
    const int tid = threadIdx.x, j = tid & (G - 1), gh = tid >> 7;
    const long long bt0 = (long long)blockIdx.x * 4 + gh * 2;
    const bool f32 = flag[0] != 0;

    float wk[EMB], bj;
    if (f32) {
        const float* W = (const float*)Wk;
#pragma unroll
        for (int e = 0; e < EMB; ++e) wk[e] = W[e * G + j];
        bj = ((const float*)bias)[j];
    } else {
        const unsigned short* W = (const unsigned short*)Wk;
#pragma unroll
        for (int e = 0; e < EMB; ++e) wk[e] = bf2f(W[e * G + j]);
        bj = bf2f(((const unsigned short*)bias)[j]);
    }

#pragma unroll
    for (int r = 0; r < 2; ++r) {
        const long long bt = bt0 + r;
        const int tok = tokens[bt];
        float x[EMB];
        if (f32) {
            const uint4* p = (const uint4*)((const float*)emb + (size_t)tok * EMB);
            const uint4 a = p[0], b2 = p[1], c2 = p[2], d2 = p[3];
            const unsigned w[16] = {a.x,a.y,a.z,a.w, b2.x,b2.y,b2.z,b2.w,
                                    c2.x,c2.y,c2.z,c2.w, d2.x,d2.y,d2.z,d2.w};
#pragma unroll
            for (int e = 0; e < 16; ++e) x[e] = __uint_as_float(w[e]);
        } else {
            const uint4* p = (const uint4*)((const unsigned short*)emb + (size_t)tok * EMB);
            const uint4 a = p[0], b2 = p[1];
            const unsigned w[8] = {a.x,a.y,a.z,a.w, b2.x,b2.y,b2.z,b2.w};
#pragma unroll
            for (int q = 0; q < 8; ++q) {
                x[2*q]   = __uint_as_float(w[q] << 16);
                x[2*q+1] = __uint_as_float(w[q] & 0xFFFF0000u);
            }
        }
        float acc = bj;
#pragma unroll
        for (int e = 0; e < EMB; ++e) acc = fmaf(x[e], wk[e], acc);
        zx[bt * G + j] = acc;
    }
}

// ---------------------------------------------------------------------------
// Scan (workspace path): one wave per sequence. Lane j<32 owns cols (i_j,g_j),
// lane j>=32 owns (f,o). h broadcast via v_readlane; gate exchange via
// shfl_xor(32); mask via per-chunk ballot word. No LDS, no barriers in loop.
// ---------------------------------------------------------------------------
template <bool F32OUT>
__device__ __forceinline__ void scan_ws_loop(
    const int* __restrict__ trow, const float* __restrict__ zrow, void* orow,
    const float (&wra)[HID], const float (&wrb)[HID], int lane)
{
    const bool  lo  = lane < HID;
    const float zsc = lo ? 2.f : 1.f, gm = lo ? 2.f : 1.f, ga = lo ? -1.f : 0.f;
    float h = 0.f, c = 0.f;

    float pza[4], pzb[4];
#pragma unroll
    for (int p = 0; p < 4; ++p) {
        pza[p] = zrow[p * G + lane];
        pzb[p] = zrow[p * G + lane + 64];
    }
    int tk = trow[lane];

    for (int ch = 0; ch < TT / 64; ++ch) {
        const unsigned long long mw = __ballot(tk != 0);
        if (ch < TT / 64 - 1) tk = trow[(ch + 1) * 64 + lane];
        const int tb = ch * 64;
        for (int i = 0; i < 64; i += 4) {
#pragma unroll
            for (int u = 0; u < 4; ++u) {
                const int t = tb + i + u;
                float za = pza[u], zb = pzb[u];
                int tp = t + 4; tp = tp > TT - 1 ? TT - 1 : tp;
                pza[u] = zrow[(long long)tp * G + lane];
                pzb[u] = zrow[(long long)tp * G + lane + 64];
#pragma unroll
                for (int k = 0; k < HID; ++k) {
                    const float hk = rdl(h, k);
                    za = fmaf(hk, wra[k], za);
                    zb = fmaf(hk, wrb[k], zb);
                }
                const float a1 = sigm(za);
                const float s2 = sigm(zb * zsc);
                const float a2 = fmaf(s2, gm, ga);
                const float x1 = __shfl_xor(a1, 32);
                const float x2 = __shfl_xor(a2, 32);
                const float iV = lo ? a1 : x1, fV = lo ? x1 : a1;
                const float gV = lo ? a2 : x2, oV = lo ? x2 : a2;
                const float cN = fmaf(fV, c, iV * gV);
                const float hN = oV * tanh_f(cN);
                const bool  m  = (mw >> (i + u)) & 1ull;
                c = m ? cN : c;
                h = m ? hN : h;
                const int oi = t * HID + (lane & (HID - 1));   // both halves: same addr+data
                if (F32OUT) ((float*)orow)[oi] = h;
                else        ((unsigned short*)orow)[oi] = f2bf(h);
            }
        }
    }
}

__global__ __launch_bounds__(64) void scan_ws_kernel(
    const int* __restrict__ tokens, const float* __restrict__ zx,
    const void* __restrict__ Wr, void* __restrict__ out,
    const int* __restrict__ flag)
{
    const int lane = threadIdx.x, b = blockIdx.x;
    const bool f32 = flag[0] != 0;

    float wra[HID], wrb[HID];
    if (f32) {
        const float* W = (const float*)Wr;
#pragma unroll
        for (int k = 0; k < HID; ++k) { wra[k] = W[k*G + lane]; wrb[k] = W[k*G + lane + 64]; }
    } else {
        const unsigned short* W = (const unsigned short*)Wr;
#pragma unroll
        for (int k = 0; k < HID; ++k) { wra[k] = bf2f(W[k*G + lane]); wrb[k] = bf2f(W[k*G + lane + 64]); }
    }
    const int*   trow = tokens + (long long)b * TT;
    const float* zrow = zx + (long long)b * TT * G;
    if (f32) scan_ws_loop<true >(trow, zrow, (char*)out + (long long)b*TT*HID*4, wra, wrb, lane);
    else     scan_ws_loop<false>(trow, zrow, (char*)out + (long long)b*TT*HID*2, wra, wrb, lane);
}

// ---------------------------------------------------------------------------
// Fused fallback (no workspace): computes x@Wk inline, emb row prefetch depth 2.
// ---------------------------------------------------------------------------
template <bool F32>
__device__ __forceinline__ void row_load(const void* emb, int tok, uint4* r) {
    if (F32) { const uint4* p = (const uint4*)((const float*)emb + (size_t)tok*EMB);
               r[0]=p[0]; r[1]=p[1]; r[2]=p[2]; r[3]=p[3]; }
    else     { const uint4* p = (const uint4*)((const unsigned short*)emb + (size_t)tok*EMB);
               r[0]=p[0]; r[1]=p[1]; }
}
template <bool F32>
__device__ __forceinline__ void row_unpack(const uint4* r, float* x) {
    if (F32) {
        const unsigned w[16] = {r[0].x,r[0].y,r[0].z,r[0].w, r[1].x,r[1].y,r[1].z,r[1].w,
                                r[2].x,r[2].y,r[2].z,r[2].w, r[3].x,r[3].y,r[3].z,r[3].w};
#pragma unroll
        for (int e = 0; e < 16; ++e) x[e] = __uint_as_float(w[e]);
    } else {
        const unsigned w[8] = {r[0].x,r[0].y,r[0].z,r[0].w, r[1].x,r[1].y,r[1].z,r[1].w};
#pragma unroll
        for (int q = 0; q < 8; ++q) {
            x[2*q]   = __uint_as_float(w[q] << 16);
            x[2*q+1] = __uint_as_float(w[q] & 0xFFFF0000u);
        }
    }
}

template <bool F32>
__device__ __forceinline__ void scan_fused_loop(
    const int* __restrict__ trow, const void* __restrict__ emb, void* orow,
    const float (&wka)[EMB], const float (&wkb)[EMB],
    const float (&wra)[HID], const float (&wrb)[HID],
    float za0, float zb0, const int* tl, int lane)
{
    const bool  lo  = lane < HID;
    const float zsc = lo ? 2.f : 1.f, gm = lo ? 2.f : 1.f, ga = lo ? -1.f : 0.f;
    float h = 0.f, c = 0.f;
    uint4 praw[2][4];
    row_load<F32>(emb, trow[0], praw[0]);
    row_load<F32>(emb, trow[1], praw[1]);

    for (int tt = 0; tt < TT; tt += 2) {
#pragma unroll
        for (int u = 0; u < 2; ++u) {
            const int t = tt + u;
            float x[EMB];
            row_unpack<F32>(praw[u], x);
            int tn = t + 2; tn = tn > TT - 1 ? TT - 1 : tn;
            row_load<F32>(emb, tl[tn], praw[u]);
            float za = za0, zb = zb0;
#pragma unroll
            for (int e = 0; e < EMB; ++e) { za = fmaf(x[e], wka[e], za); zb = fmaf(x[e], wkb[e], zb); }
#pragma unroll
            for (int k = 0; k < HID; ++k) {
                const float hk = rdl(h, k);
                za = fmaf(hk, wra[k], za);
                zb = fmaf(hk, wrb[k], zb);
            }
            const float a1 = sigm(za);
            const float s2 = sigm(zb * zsc);
            const float a2 = fmaf(s2, gm, ga);
            const float x1 = __shfl_xor(a1, 32);
            const float x2 = __shfl_xor(a2, 32);
            const float iV = lo ? a1 : x1, fV = lo ? x1 : a1;
            const float gV = lo ? a2 : x2, oV = lo ? x2 : a2;
            const float cN = fmaf(fV, c, iV * gV);
            const float hN = oV * tanh_f(cN);
            const bool  m  = tl[t] != 0;
            c = m ? cN : c;
            h = m ? hN : h;
            const int oi = t * HID + (lane & (HID - 1));
            if (F32) ((float*)orow)[oi] = h;
            else     ((unsigned short*)orow)[oi] = f2bf(h);
        }
    }
}

__global__ __launch_bounds__(64) void scan_fused_kernel(
    const int* __restrict__ tokens, const void* __restrict__ emb,
    const void* __restrict__ Wk, const void* __restrict__ Wr,
    const void* __restrict__ bias, void* __restrict__ out,
    const int* __restrict__ flag, int defmode)
{
    __shared__ int tl[TT];
    const int lane = threadIdx.x, b = blockIdx.x;
    const bool f32 = flag ? (flag[0] != 0) : (defmode != 0);
    const int* trow = tokens + (long long)b * TT;
    for (int t = lane; t < TT; t += 64) tl[t] = trow[t];

    float wka[EMB], wkb[EMB], wra[HID], wrb[HID], za0, zb0;
    if (f32) {
        const float* WK = (const float*)Wk; const float* WR = (const float*)Wr;
        const float* B  = (const float*)bias;
#pragma unroll
        for (int e = 0; e < EMB; ++e) { wka[e] = WK[e*G + lane]; wkb[e] = WK[e*G + lane + 64]; }
#pragma unroll
        for (int k = 0; k < HID; ++k) { wra[k] = WR[k*G + lane]; wrb[k] = WR[k*G + lane + 64]; }
        za0 = B[lane]; zb0 = B[lane + 64];
    } else {
        const unsigned short* WK = (const unsigned short*)Wk;
        const unsigned short* WR = (const unsigned short*)Wr;
        const unsigned short* B  = (const unsigned short*)bias;
#pragma unroll
        for (int e = 0; e < EMB; ++e) { wka[e] = bf2f(WK[e*G + lane]); wkb[e] = bf2f(WK[e*G + lane + 64]); }
#pragma unroll
        for (int k = 0; k < HID; ++k) { wra[k] = bf2f(WR[k*G + lane]); wrb[k] = bf2f(WR[k*G + lane + 64]); }
        za0 = bf2f(B[lane]); zb0 = bf2f(B[lane + 64]);
    }
    __syncthreads();

    if (f32) scan_fused_loop<true >(trow, emb, (char*)out + (long long)b*TT*HID*4,
                                    wka, wkb, wra, wrb, za0, zb0, tl, lane);
    else     scan_fused_loop<false>(trow, emb, (char*)out + (long long)b*TT*HID*2,
                                    wka, wkb, wra, wrb, za0, zb0, tl, lane);
}

// ---------------------------------------------------------------------------
extern "C" void kernel_launch(void* const* d_in, const int* in_sizes, int n_in,
                              void* d_out, int out_size, void* d_ws, size_t ws_size,
                              hipStream_t stream) {
    const int*  tokens = (const int*)d_in[0];
    const void* emb    = d_in[1];
    const void* Wk     = d_in[2];
    const void* Wr     = d_in[3];
    const void* bias   = d_in[4];

    const size_t zx_off   = 256;
    const size_t zx_bytes = (size_t)BB * TT * G * sizeof(float);   // 256 MB

    if (ws_size >= 16) {
        int* flag = (int*)d_ws;
        detect_kernel<<<1, 64, 0, stream>>>((const unsigned int*)bias, flag);
        if (ws_size >= zx_off + zx_bytes) {
            float* zx = (float*)((char*)d_ws + zx_off);
            zx_kernel<<<(BB * TT) / 4, 256, 0, stream>>>(tokens, emb, Wk, bias, zx, flag);
            scan_ws_kernel<<<BB, 64, 0, stream>>>(tokens, zx, Wr, d_out, flag);
        } else {
            scan_fused_kernel<<<BB, 64, 0, stream>>>(tokens, emb, Wk, Wr, bias, d_out, flag, 1);
        }
    } else {
        // no workspace at all: assume documented contract (fp32)
        scan_fused_kernel<<<BB, 64, 0, stream>>>(tokens, emb, Wk, Wr, bias, d_out, nullptr, 1);
    }
}

// Round 3
// 607.753 us; speedup vs baseline: 1.4559x; 1.4559x over previous
//
#include <hip/hip_runtime.h>

#define G    128          // 4*HID
#define HID  32
#define EMB  16
#define BB   256
#define TT   2048
#define VOC  5000

typedef float v2f __attribute__((ext_vector_type(2)));

__device__ __forceinline__ float bf2f(unsigned short u) {
    return __uint_as_float(((unsigned)u) << 16);
}
__device__ __forceinline__ unsigned short f2bf(float f) {
    unsigned x = __float_as_uint(f);
    return (unsigned short)((x + 0x7FFFu + ((x >> 16) & 1u)) >> 16);  // RNE
}
__device__ __forceinline__ float rdl(float v, int k) {
    return __int_as_float(__builtin_amdgcn_readlane(__float_as_int(v), k));
}
__device__ __forceinline__ float sigm(float x) {
    const float e = __expf(-x);
    return __builtin_amdgcn_rcpf(1.f + e);
}
__device__ __forceinline__ float tanh_f(float x) {
    const float e = __expf(-2.f * x);
    return (1.f - e) * __builtin_amdgcn_rcpf(1.f + e);
}
__device__ __forceinline__ void pkfma(v2f& acc, float s, v2f w) {
    acc.x = fmaf(s, w.x, acc.x);
    acc.y = fmaf(s, w.y, acc.y);
}

// ---------------------------------------------------------------------------
// Dtype detector (flag=1 -> fp32 buffers, flag=0 -> bf16 buffers).
// ---------------------------------------------------------------------------
__global__ void detect_kernel(const unsigned int* __restrict__ bias_w,
                              int* __restrict__ flag) {
    if (threadIdx.x == 0 && blockIdx.x == 0) {
        bool evens_zero = true, anybig = false;
        for (int i = 0; i < 64; ++i) {
            const unsigned u  = bias_w[i];
            const unsigned lo = u & 0xFFFFu, hi = u >> 16;
            const float vlo = __uint_as_float(lo << 16);
            const float vhi = __uint_as_float(hi << 16);
            if (lo != 0u) evens_zero = false;
            if (!(fabsf(vlo) < 1e6f) || !(fabsf(vhi) < 1e6f)) anybig = true;
        }
        *flag = (evens_zero || anybig) ? 1 : 0;
    }
}

// ---------------------------------------------------------------------------
// Token z-table: ZK[v][2l]   = b[l]    + sum_e emb[v][e]*Wk[e][l]
//                ZK[v][2l+1] = b[l+64] + sum_e emb[v][e]*Wk[e][l+64]
// Permuted layout: lane l of the scan loads one dwordx2 at offset 2l.
// ---------------------------------------------------------------------------
__global__ __launch_bounds__(64) void zk_kernel(
    const void* __restrict__ emb, const void* __restrict__ Wk,
    const void* __restrict__ bias, float* __restrict__ ZK,
    const int* __restrict__ flag)
{
    const int l = threadIdx.x;          // 0..63
    const int v = blockIdx.x;           // 0..VOC-1
    const bool f32 = flag[0] != 0;

    float x[EMB], wa[EMB], wb[EMB], ba, bb;
    if (f32) {
        const float* E = (const float*)emb + (size_t)v * EMB;
        const float* W = (const float*)Wk;
        const float* B = (const float*)bias;
#pragma unroll
        for (int e = 0; e < EMB; ++e) {
            x[e]  = E[e];
            wa[e] = W[e * G + l];
            wb[e] = W[e * G + l + 64];
        }
        ba = B[l]; bb = B[l + 64];
    } else {
        const unsigned short* E = (const unsigned short*)emb + (size_t)v * EMB;
        const unsigned short* W = (const unsigned short*)Wk;
        const unsigned short* B = (const unsigned short*)bias;
#pragma unroll
        for (int e = 0; e < EMB; ++e) {
            x[e]  = bf2f(E[e]);
            wa[e] = bf2f(W[e * G + l]);
            wb[e] = bf2f(W[e * G + l + 64]);
        }
        ba = bf2f(B[l]); bb = bf2f(B[l + 64]);
    }
    float za = ba, zb = bb;
#pragma unroll
    for (int e = 0; e < EMB; ++e) {
        za = fmaf(x[e], wa[e], za);
        zb = fmaf(x[e], wb[e], zb);
    }
    ZK[(size_t)v * G + 2 * l]     = za;
    ZK[(size_t)v * G + 2 * l + 1] = zb;
}

// ---------------------------------------------------------------------------
// Fast scan: one wave per sequence. z_x via one dwordx2 gather from ZK
// (prefetch depth 4). Tokens chunked 16 in (scalar) registers, prefetched one
// chunk ahead. h broadcast via readlane; 4 independent fma chains (depth 8).
// ---------------------------------------------------------------------------
template <bool F32OUT>
__device__ __forceinline__ void scan_zk_loop(
    const int* __restrict__ trow, const float* __restrict__ ZK,
    void* __restrict__ orow, const v2f (&wr2)[HID], int lane)
{
    const bool  lo  = lane < HID;
    const float zsc = lo ? 2.f : 1.f, gm = lo ? 2.f : 1.f, ga = lo ? -1.f : 0.f;
    const int   oj  = lane & (HID - 1);
    float h = 0.f, c = 0.f;

    int tcur[16], tnxt[16];
#pragma unroll
    for (int p = 0; p < 16; ++p) tcur[p] = trow[p];
#pragma unroll
    for (int p = 0; p < 16; ++p) tnxt[p] = trow[16 + p];

    v2f pz[4];
#pragma unroll
    for (int d = 0; d < 4; ++d)
        pz[d] = *(const v2f*)(ZK + (size_t)tcur[d] * G + 2 * lane);

    for (int cc = 0; cc < TT / 16; ++cc) {
        const int base = cc * 16;
#pragma unroll
        for (int u = 0; u < 16; ++u) {
            const int t = base + u;
            const v2f z = pz[u & 3];
            // prefetch z for t+4 (token from current/next chunk regs; any
            // stale token at the tail is still a valid row -> harmless)
            const int ptok = (u + 4 < 16) ? tcur[u + 4] : tnxt[u + 4 - 16];
            pz[u & 3] = *(const v2f*)(ZK + (size_t)ptok * G + 2 * lane);

            // h @ Wr : 4 independent packed chains of 8
            v2f a0 = z, a1 = {0.f, 0.f}, a2 = {0.f, 0.f}, a3 = {0.f, 0.f};
#pragma unroll
            for (int k = 0; k < 8; ++k) {
                pkfma(a0, rdl(h, k),      wr2[k]);
                pkfma(a1, rdl(h, k + 8),  wr2[k + 8]);
                pkfma(a2, rdl(h, k + 16), wr2[k + 16]);
                pkfma(a3, rdl(h, k + 24), wr2[k + 24]);
            }
            a0.x += a1.x; a0.y += a1.y;
            a2.x += a3.x; a2.y += a3.y;
            const float za = a0.x + a2.x;
            const float zb = a0.y + a2.y;

            const float aa1 = sigm(za);
            const float s2  = sigm(zb * zsc);
            const float aa2 = fmaf(s2, gm, ga);
            const float x1  = __shfl_xor(aa1, 32);
            const float x2  = __shfl_xor(aa2, 32);
            const float iV = lo ? aa1 : x1, fV = lo ? x1 : aa1;
            const float gV = lo ? aa2 : x2, oV = lo ? x2 : aa2;
            const float cN = fmaf(fV, c, iV * gV);
            const float hN = oV * tanh_f(cN);
            const bool  m  = tcur[u] != 0;
            c = m ? cN : c;
            h = m ? hN : h;

            const int oi = t * HID + oj;     // both halves: same addr+data
            if (F32OUT) __builtin_nontemporal_store(h, &((float*)orow)[oi]);
            else        __builtin_nontemporal_store(f2bf(h), &((unsigned short*)orow)[oi]);
        }
        // rotate token chunks, prefetch chunk cc+2
#pragma unroll
        for (int p = 0; p < 16; ++p) tcur[p] = tnxt[p];
        const int nb = (cc + 2) * 16;
        if (nb <= TT - 16) {
#pragma unroll
            for (int p = 0; p < 16; ++p) tnxt[p] = trow[nb + p];
        }
    }
}

__global__ __launch_bounds__(64) void scan_zk_kernel(
    const int* __restrict__ tokens, const float* __restrict__ ZK,
    const void* __restrict__ Wr, void* __restrict__ out,
    const int* __restrict__ flag)
{
    const int lane = threadIdx.x, b = blockIdx.x;
    const bool f32 = flag[0] != 0;

    v2f wr2[HID];
    if (f32) {
        const float* W = (const float*)Wr;
#pragma unroll
        for (int k = 0; k < HID; ++k) {
            wr2[k].x = W[k * G + lane];
            wr2[k].y = W[k * G + lane + 64];
        }
    } else {
        const unsigned short* W = (const unsigned short*)Wr;
#pragma unroll
        for (int k = 0; k < HID; ++k) {
            wr2[k].x = bf2f(W[k * G + lane]);
            wr2[k].y = bf2f(W[k * G + lane + 64]);
        }
    }
    const int* trow = tokens + (long long)b * TT;
    if (f32) scan_zk_loop<true >(trow, ZK, (char*)out + (long long)b * TT * HID * 4, wr2, lane);
    else     scan_zk_loop<false>(trow, ZK, (char*)out + (long long)b * TT * HID * 2, wr2, lane);
}

// ---------------------------------------------------------------------------
// Fallback (no workspace): proven R2 fused kernel.
// ---------------------------------------------------------------------------
template <bool F32>
__device__ __forceinline__ void row_load(const void* emb, int tok, uint4* r) {
    if (F32) { const uint4* p = (const uint4*)((const float*)emb + (size_t)tok*EMB);
               r[0]=p[0]; r[1]=p[1]; r[2]=p[2]; r[3]=p[3]; }
    else     { const uint4* p = (const uint4*)((const unsigned short*)emb + (size_t)tok*EMB);
               r[0]=p[0]; r[1]=p[1]; }
}
template <bool F32>
__device__ __forceinline__ void row_unpack(const uint4* r, float* x) {
    if (F32) {
        const unsigned w[16] = {r[0].x,r[0].y,r[0].z,r[0].w, r[1].x,r[1].y,r[1].z,r[1].w,
                                r[2].x,r[2].y,r[2].z,r[2].w, r[3].x,r[3].y,r[3].z,r[3].w};
#pragma unroll
        for (int e = 0; e < 16; ++e) x[e] = __uint_as_float(w[e]);
    } else {
        const unsigned w[8] = {r[0].x,r[0].y,r[0].z,r[0].w, r[1].x,r[1].y,r[1].z,r[1].w};
#pragma unroll
        for (int q = 0; q < 8; ++q) {
            x[2*q]   = __uint_as_float(w[q] << 16);
            x[2*q+1] = __uint_as_float(w[q] & 0xFFFF0000u);
        }
    }
}

template <bool F32>
__device__ __forceinline__ void scan_fused_loop(
    const int* __restrict__ trow, const void* __restrict__ emb, void* orow,
    const float (&wka)[EMB], const float (&wkb)[EMB],
    const float (&wra)[HID], const float (&wrb)[HID],
    float za0, float zb0, const int* tl, int lane)
{
    const bool  lo  = lane < HID;
    const float zsc = lo ? 2.f : 1.f, gm = lo ? 2.f : 1.f, ga = lo ? -1.f : 0.f;
    float h = 0.f, c = 0.f;
    uint4 praw[2][4];
    row_load<F32>(emb, trow[0], praw[0]);
    row_load<F32>(emb, trow[1], praw[1]);

    for (int tt = 0; tt < TT; tt += 2) {
#pragma unroll
        for (int u = 0; u < 2; ++u) {
            const int t = tt + u;
            float x[EMB];
            row_unpack<F32>(praw[u], x);
            int tn = t + 2; tn = tn > TT - 1 ? TT - 1 : tn;
            row_load<F32>(emb, tl[tn], praw[u]);
            float za = za0, zb = zb0;
#pragma unroll
            for (int e = 0; e < EMB; ++e) { za = fmaf(x[e], wka[e], za); zb = fmaf(x[e], wkb[e], zb); }
#pragma unroll
            for (int k = 0; k < HID; ++k) {
                const float hk = rdl(h, k);
                za = fmaf(hk, wra[k], za);
                zb = fmaf(hk, wrb[k], zb);
            }
            const float a1 = sigm(za);
            const float s2 = sigm(zb * zsc);
            const float a2 = fmaf(s2, gm, ga);
            const float x1 = __shfl_xor(a1, 32);
            const float x2 = __shfl_xor(a2, 32);
            const float iV = lo ? a1 : x1, fV = lo ? x1 : a1;
            const float gV = lo ? a2 : x2, oV = lo ? x2 : a2;
            const float cN = fmaf(fV, c, iV * gV);
            const float hN = oV * tanh_f(cN);
            const bool  m  = tl[t] != 0;
            c = m ? cN : c;
            h = m ? hN : h;
            const int oi = t * HID + (lane & (HID - 1));
            if (F32) ((float*)orow)[oi] = h;
            else     ((unsigned short*)orow)[oi] = f2bf(h);
        }
    }
}

__global__ __launch_bounds__(64) void scan_fused_kernel(
    const int* __restrict__ tokens, const void* __restrict__ emb,
    const void* __restrict__ Wk, const void* __restrict__ Wr,
    const void* __restrict__ bias, void* __restrict__ out,
    const int* __restrict__ flag, int defmode)
{
    __shared__ int tl[TT];
    const int lane = threadIdx.x, b = blockIdx.x;
    const bool f32 = flag ? (flag[0] != 0) : (defmode != 0);
    const int* trow = tokens + (long long)b * TT;
    for (int t = lane; t < TT; t += 64) tl[t] = trow[t];

    float wka[EMB], wkb[EMB], wra[HID], wrb[HID], za0, zb0;
    if (f32) {
        const float* WK = (const float*)Wk; const float* WR = (const float*)Wr;
        const float* B  = (const float*)bias;
#pragma unroll
        for (int e = 0; e < EMB; ++e) { wka[e] = WK[e*G + lane]; wkb[e] = WK[e*G + lane + 64]; }
#pragma unroll
        for (int k = 0; k < HID; ++k) { wra[k] = WR[k*G + lane]; wrb[k] = WR[k*G + lane + 64]; }
        za0 = B[lane]; zb0 = B[lane + 64];
    } else {
        const unsigned short* WK = (const unsigned short*)Wk;
        const unsigned short* WR = (const unsigned short*)Wr;
        const unsigned short* B  = (const unsigned short*)bias;
#pragma unroll
        for (int e = 0; e < EMB; ++e) { wka[e] = bf2f(WK[e*G + lane]); wkb[e] = bf2f(WK[e*G + lane + 64]); }
#pragma unroll
        for (int k = 0; k < HID; ++k) { wra[k] = bf2f(WR[k*G + lane]); wrb[k] = bf2f(WR[k*G + lane + 64]); }
        za0 = bf2f(B[lane]); zb0 = bf2f(B[lane + 64]);
    }
    __syncthreads();

    if (f32) scan_fused_loop<true >(trow, emb, (char*)out + (long long)b*TT*HID*4,
                                    wka, wkb, wra, wrb, za0, zb0, tl, lane);
    else     scan_fused_loop<false>(trow, emb, (char*)out + (long long)b*TT*HID*2,
                                    wka, wkb, wra, wrb, za0, zb0, tl, lane);
}

// ---------------------------------------------------------------------------
extern "C" void kernel_launch(void* const* d_in, const int* in_sizes, int n_in,
                              void* d_out, int out_size, void* d_ws, size_t ws_size,
                              hipStream_t stream) {
    const int*  tokens = (const int*)d_in[0];
    const void* emb    = d_in[1];
    const void* Wk     = d_in[2];
    const void* Wr     = d_in[3];
    const void* bias   = d_in[4];

    const size_t zk_off   = 256;
    const size_t zk_bytes = (size_t)VOC * G * sizeof(float);   // 2.56 MB

    if (ws_size >= zk_off + zk_bytes) {
        int*   flag = (int*)d_ws;
        float* ZK   = (float*)((char*)d_ws + zk_off);
        detect_kernel<<<1, 64, 0, stream>>>((const unsigned int*)bias, flag);
        zk_kernel<<<VOC, 64, 0, stream>>>(emb, Wk, bias, ZK, flag);
        scan_zk_kernel<<<BB, 64, 0, stream>>>(tokens, ZK, Wr, d_out, flag);
    } else if (ws_size >= 16) {
        int* flag = (int*)d_ws;
        detect_kernel<<<1, 64, 0, stream>>>((const unsigned int*)bias, flag);
        scan_fused_kernel<<<BB, 64, 0, stream>>>(tokens, emb, Wk, Wr, bias, d_out, flag, 1);
    } else {
        scan_fused_kernel<<<BB, 64, 0, stream>>>(tokens, emb, Wk, Wr, bias, d_out, nullptr, 1);
    }
}